// Round 4
// baseline (103.961 us; speedup 1.0000x reference)
//
#include <hip/hip_runtime.h>
#include <math.h>

#define EPS_F 1e-6f
#define S_DIM 768
#define W_DIM 32
#define H_DIM 12
#define NK 33   // intervals = W_DIM + 1

// Fully fused: every block builds the (tiny) PWL tables for its own head h in
// LDS, then evaluates 4 rows (one wave per row). No setup kernel, no ws use.
//
// Layout change vs r3: segment-coalesced IO. Lane holds elements at columns
// 256*seg + 4*lane + j (seg=0..2, j=0..3), so every global load/store
// instruction is a fully-contiguous 1 KiB wave transaction.
//
// Table semantics (identical to the verified versions):
//   sh[0..32)  sorted hinge values (ascending, ties by original index)
//   sAB[2k],sAB[2k+1] = A_k,B_k for interval k, B_k includes b_out[h].

__global__ __launch_bounds__(256) void cope_fused_kernel(
    const float* __restrict__ attn,   // (H*S, S)
    const float* __restrict__ W_in, const float* __restrict__ b_in,
    const float* __restrict__ W_out, const float* __restrict__ b_out,
    const float* __restrict__ c_p,
    const float* __restrict__ Lm_p,
    const float* __restrict__ iL_p,
    float* __restrict__ out)
{
    const int t    = threadIdx.x;
    const int lane = t & 63;
    const int wave = t >> 6;
    const int row  = blockIdx.x * 4 + wave;       // one wave per row
    const int h    = blockIdx.x / (S_DIM / 4);    // 192 blocks per h (exact)

    __shared__ __align__(16) float sh[W_DIM];     // sorted hinges (b128-aligned)
    __shared__ __align__(8)  float sAB[2 * NK];   // A,B pairs for this h
    __shared__ float th_s[W_DIM];                 // unsorted hinges
    __shared__ float sWin[W_DIM], sBin[W_DIM], sWout[W_DIM];
    __shared__ int   rk_s[W_DIM];                 // rank of hinge w
    __shared__ float pA[4 * NK], pB[4 * NK];      // partial A/B sums

    // ---- issue global loads first (latency hides under table build) -------
    // segment-coalesced: each load is 64 lanes x 16B contiguous (1 KiB)
    const float* rowp = attn + (size_t)row * S_DIM + lane * 4;
    float4 v0 = *(const float4*)(rowp);           // cols [  0..256)
    float4 v1 = *(const float4*)(rowp + 256);     // cols [256..512)
    float4 v2 = *(const float4*)(rowp + 512);     // cols [512..768)
    const float c   = c_p[0];
    const float thr = fabsf(Lm_p[0] * iL_p[0]);

    // ---- table build step 1: hinges + cache weights in LDS ----
    if (t < W_DIM) {
        float w1 = W_in[t], b = b_in[t];
        th_s[t] = (w1 != 0.0f) ? (-b / w1) : __builtin_inff();
        sWin[t] = w1;
        sBin[t] = b;
        sWout[t] = W_out[h * W_DIM + t];
    }
    __syncthreads();

    // ---- step 2: rank (ties by index) -> sorted hinge array ----
    if (t < W_DIM) {
        float mine = th_s[t];
        int r = 0;
        for (int v = 0; v < W_DIM; v++) {
            float o = th_s[v];
            if (o < mine || (o == mine && v < t)) r++;
        }
        rk_s[t] = r;
        sh[r]   = mine;
    }
    __syncthreads();

    // ---- step 3: A/B partial sums, 4 threads per interval k (t < 132) ----
    if (t < 4 * NK) {
        const int k = t >> 2, q = t & 3;
        float A = 0.0f, B = 0.0f;
#pragma unroll
        for (int j = 0; j < 8; j++) {
            const int w = q * 8 + j;
            float w1 = sWin[w], bv = sBin[w], ov = sWout[w];
            int   r  = rk_s[w];
            bool active = (w1 > 0.0f) ? (k > r)
                        : (w1 < 0.0f) ? (k <= r)
                        : (bv > 0.0f);
            if (active) { A += w1 * ov; B += bv * ov; }
        }
        pA[t] = A;
        pB[t] = B;
    }
    __syncthreads();

    // ---- step 4: combine partials (t < 33); overlaps with sigmoid below ---
    if (t < NK) {
        float A = (pA[4*t] + pA[4*t+1]) + (pA[4*t+2] + pA[4*t+3]);
        float B = (pB[4*t] + pB[4*t+1]) + (pB[4*t+2] + pB[4*t+3]) + b_out[h];
        sAB[2*t]     = A;
        sAB[2*t + 1] = B;
    }

    // ---- table-independent element compute (all threads, hides step 4) ----
    // g[s*4+j] = sigmoid of element at column 256*s + 4*lane + j
    float g[12] = { v0.x, v0.y, v0.z, v0.w, v1.x, v1.y, v1.z, v1.w,
                    v2.x, v2.y, v2.z, v2.w };
#pragma unroll
    for (int i = 0; i < 12; i++)
        g[i] = __builtin_amdgcn_rcpf(1.0f + __expf(-g[i]));

    // per-segment lane totals; three independent scans in lockstep (3-way ILP)
    float G0 = (g[0] + g[1]) + (g[2] + g[3]);
    float G1 = (g[4] + g[5]) + (g[6] + g[7]);
    float G2 = (g[8] + g[9]) + (g[10] + g[11]);
    float P0 = G0, P1 = G1, P2 = G2;
#pragma unroll
    for (int d = 1; d < 64; d <<= 1) {
        float y0 = __shfl_up(P0, d, 64);
        float y1 = __shfl_up(P1, d, 64);
        float y2 = __shfl_up(P2, d, 64);
        if (lane >= d) { P0 += y0; P1 += y1; P2 += y2; }
    }
    const float tot0 = __shfl(P0, 63, 64);
    const float tot1 = __shfl(P1, 63, 64);
    const float tot2 = __shfl(P2, 63, 64);
    const float total = (tot0 + tot1) + tot2;     // suffix at col 0 == max_pos

    // suffix sum starting at this lane's first element of each segment
    const float base0 = total - P0 + G0;                  // + (tot1+tot2) folded
    const float base1 = (tot1 + tot2) - P1 + G1;
    const float base2 = tot2 - P2 + G2;

    const float den      = __logf(fabsf(c * fminf(total, thr)) + 1.0f) + EPS_F;
    // fold ln2 into inv_den so per-element log is raw v_log_f32 (log2)
    const float inv_den2 = 0.69314718056f * __builtin_amdgcn_rcpf(den);

    // phase 1: all 12 dist values (3 short independent chains)
    float dv[12];
    {
        const float bases[3] = { base0, base1, base2 };
#pragma unroll
        for (int s = 0; s < 3; s++) {
            float e = 0.0f;
#pragma unroll
            for (int j = 0; j < 4; j++) {
                float pos = bases[s] - e;        // suffix sum at element (s,j)
                e += g[s * 4 + j];
                dv[s * 4 + j] = __log2f(fabsf(c * pos) + 1.0f) * inv_den2;
            }
        }
    }

    __syncthreads();   // tables complete

    // uniform hinge scalars for the register-select levels (LDS broadcasts)
    const float s3  = sh[3],  s7  = sh[7],  s11 = sh[11], s15 = sh[15];
    const float s19 = sh[19], s23 = sh[23], s27 = sh[27];

    // ---- phase 2: PWL search, two half-batches of 6 for explicit MLP ------
    float o[12];
#pragma unroll
    for (int half = 0; half < 2; half++) {
        const int i0 = half * 6;

        int    k4[6];
        float4 r[6];
#pragma unroll
        for (int j = 0; j < 6; j++) {
            const float d = dv[i0 + j];
            int k = 0;
            bool b1 = (s15 < d);             if (b1) k += 16;
            float l2 = b1 ? s23 : s7;
            bool b2 = (l2 < d);              if (b2) k += 8;
            float l3a = b2 ? s11 : s3;
            float l3b = b2 ? s27 : s19;
            float l3  = b1 ? l3b : l3a;
            if (l3 < d) k += 4;
            k4[j] = k;                       // k in {0,4,...,28}
        }
        // issue all 6 b128 reads (aligned; 8 distinct 16B slots tile banks)
#pragma unroll
        for (int j = 0; j < 6; j++)
            r[j] = *(const float4*)(&sh[k4[j]]);

        // resolve final k via register selects, then the 6 A/B reads
        float2 ab[6];
        float  dd[6];
#pragma unroll
        for (int j = 0; j < 6; j++) {
            const float d = dv[i0 + j];
            int k = k4[j];
            bool c2 = (r[j].y < d);          if (c2) k += 2;   // test s[k+1]
            float f1 = c2 ? r[j].z : r[j].x;                    // s[k] after +2
            bool c1 = (f1 < d);              if (c1) k += 1;
            float f0 = c1 ? (c2 ? r[j].w : r[j].y) : f1;        // s[k] after +1
            if (f0 < d) k += 1;              // final fixup -> k in [0,32]
            ab[j] = *(const float2*)(&sAB[2 * k]);
            dd[j] = d;
        }
#pragma unroll
        for (int j = 0; j < 6; j++)
            o[i0 + j] = fmaf(dd[j], ab[j].x, ab[j].y);   // A_k*d + B_k
    }

    // segment-coalesced stores: each is one contiguous 1 KiB wave transaction
    float* op = out + (size_t)row * S_DIM + lane * 4;
    *(float4*)(op)       = make_float4(o[0], o[1], o[2],  o[3]);
    *(float4*)(op + 256) = make_float4(o[4], o[5], o[6],  o[7]);
    *(float4*)(op + 512) = make_float4(o[8], o[9], o[10], o[11]);
}

extern "C" void kernel_launch(void* const* d_in, const int* in_sizes, int n_in,
                              void* d_out, int out_size, void* d_ws, size_t ws_size,
                              hipStream_t stream) {
    const float* attn  = (const float*)d_in[0];
    const float* W_in  = (const float*)d_in[1];
    const float* b_in  = (const float*)d_in[2];
    const float* W_out = (const float*)d_in[3];
    const float* b_out = (const float*)d_in[4];
    const float* c_p   = (const float*)d_in[5];
    const float* Lm_p  = (const float*)d_in[6];
    const float* iL_p  = (const float*)d_in[7];
    float* out = (float*)d_out;
    (void)d_ws; (void)ws_size;

    const int rows = H_DIM * S_DIM;            // 9216 rows, one wave each
    cope_fused_kernel<<<rows / 4, 256, 0, stream>>>(
        attn, W_in, b_in, W_out, b_out, c_p, Lm_p, iL_p, out);
}